// Round 1
// baseline (148.795 us; speedup 1.0000x reference)
//
#include <hip/hip_runtime.h>

#define LEAKY 0.2f
#define B_TOT 8192
#define N_TOT 2048
#define D_TOT 128
#define BP 16      // patients per block
#define NT 256     // n-tile size

// Kernel 1: p[b] = patient[b,:] . a_p ;  q[n] = disease[n,:] . a_n
// One wave (64 lanes) per row; 2 elements per lane; shuffle reduce.
__global__ __launch_bounds__(256) void pq_kernel(const float* __restrict__ patient,
                                                 const float* __restrict__ disease,
                                                 const float* __restrict__ ak,
                                                 float* __restrict__ p,
                                                 float* __restrict__ q) {
    int gid  = blockIdx.x * blockDim.x + threadIdx.x;
    int wid  = gid >> 6;
    int lane = gid & 63;
    const float* src;
    const float* a;
    float* dst;
    if (wid < B_TOT) {
        src = patient + (size_t)wid * D_TOT;
        a   = ak;
        dst = p + wid;
    } else {
        src = disease + (size_t)(wid - B_TOT) * D_TOT;
        a   = ak + D_TOT;
        dst = q + (wid - B_TOT);
    }
    float s = src[lane] * a[lane] + src[lane + 64] * a[lane + 64];
    #pragma unroll
    for (int off = 32; off; off >>= 1) s += __shfl_xor(s, off);
    if (lane == 0) *dst = s;
}

// Kernel 2: per block, BP patients. q[] staged in LDS; per-patient (m, S) via
// wave-parallel scan; main loop over n tiles with w-tile in LDS, each thread
// accumulates 2 patients x 4 columns.
__global__ __launch_bounds__(256) void gat_main(const float* __restrict__ patient,
                                                const float* __restrict__ disease,
                                                const float* __restrict__ p,
                                                const float* __restrict__ q,
                                                float* __restrict__ out) {
    __shared__ float q_s[N_TOT];
    __shared__ float w_s[BP][NT];
    __shared__ float m_s[BP], S_s[BP], pp_s[BP];

    const int tid = threadIdx.x;
    const int b0  = blockIdx.x * BP;

    for (int i = tid; i < N_TOT; i += 256) q_s[i] = q[i];
    if (tid < BP) pp_s[tid] = p[b0 + tid];
    __syncthreads();

    // (m, S) per patient: wave w handles patients 4w..4w+3
    const int wave = tid >> 6;
    const int lane = tid & 63;
    for (int pi = wave * 4; pi < wave * 4 + 4; ++pi) {
        float pp = pp_s[pi];
        float mx = -1e30f;
        for (int n = lane; n < N_TOT; n += 64) {
            float x = pp + q_s[n];
            x = x > 0.0f ? x : LEAKY * x;
            mx = fmaxf(mx, x);
        }
        #pragma unroll
        for (int off = 32; off; off >>= 1) mx = fmaxf(mx, __shfl_xor(mx, off));
        float sum = 0.0f;
        for (int n = lane; n < N_TOT; n += 64) {
            float x = pp + q_s[n];
            x = x > 0.0f ? x : LEAKY * x;
            sum += __expf(x - mx);
        }
        #pragma unroll
        for (int off = 32; off; off >>= 1) sum += __shfl_xor(sum, off);
        if (lane == 0) { m_s[pi] = mx; S_s[pi] = sum; }
    }
    __syncthreads();

    // main loop: thread owns cols [4*d2, 4*d2+4) for patients p0, p1
    const int d2 = tid & 31;
    const int pg = tid >> 5;
    const int p0 = 2 * pg, p1 = 2 * pg + 1;

    float4 acc0 = make_float4(0.f, 0.f, 0.f, 0.f);
    float4 acc1 = make_float4(0.f, 0.f, 0.f, 0.f);

    for (int n0 = 0; n0 < N_TOT; n0 += NT) {
        __syncthreads();  // previous tile fully consumed
        // w tile: BP x NT entries, 256 threads -> BP*NT/256 each
        for (int i = tid; i < BP * NT; i += 256) {
            int pi = i >> 8;      // NT == 256
            int nt = i & (NT - 1);
            float x = pp_s[pi] + q_s[n0 + nt];
            x = x > 0.0f ? x : LEAKY * x;
            w_s[pi][nt] = __expf(x - m_s[pi]);
        }
        __syncthreads();

        const float* drow = disease + (size_t)n0 * D_TOT + d2 * 4;
        #pragma unroll 4
        for (int nt = 0; nt < NT; ++nt) {
            float4 dv = *reinterpret_cast<const float4*>(drow + (size_t)nt * D_TOT);
            float w0 = w_s[p0][nt];
            float w1 = w_s[p1][nt];
            acc0.x += w0 * dv.x; acc0.y += w0 * dv.y;
            acc0.z += w0 * dv.z; acc0.w += w0 * dv.w;
            acc1.x += w1 * dv.x; acc1.y += w1 * dv.y;
            acc1.z += w1 * dv.z; acc1.w += w1 * dv.w;
        }
    }

    // epilogue: out = patient + acc/S
    const float inv0 = 1.0f / S_s[p0];
    const float inv1 = 1.0f / S_s[p1];
    {
        size_t off = (size_t)(b0 + p0) * D_TOT + d2 * 4;
        float4 pf = *reinterpret_cast<const float4*>(patient + off);
        float4 o;
        o.x = pf.x + acc0.x * inv0; o.y = pf.y + acc0.y * inv0;
        o.z = pf.z + acc0.z * inv0; o.w = pf.w + acc0.w * inv0;
        *reinterpret_cast<float4*>(reinterpret_cast<float*>(out) + off) = o;
    }
    {
        size_t off = (size_t)(b0 + p1) * D_TOT + d2 * 4;
        float4 pf = *reinterpret_cast<const float4*>(patient + off);
        float4 o;
        o.x = pf.x + acc1.x * inv1; o.y = pf.y + acc1.y * inv1;
        o.z = pf.z + acc1.z * inv1; o.w = pf.w + acc1.w * inv1;
        *reinterpret_cast<float4*>(reinterpret_cast<float*>(out) + off) = o;
    }
}

extern "C" void kernel_launch(void* const* d_in, const int* in_sizes, int n_in,
                              void* d_out, int out_size, void* d_ws, size_t ws_size,
                              hipStream_t stream) {
    const float* patient = (const float*)d_in[0];   // 8192 x 128
    const float* disease = (const float*)d_in[1];   // 2048 x 128
    const float* ak      = (const float*)d_in[2];   // 256 x 1
    float* out = (float*)d_out;                     // 8192 x 128

    float* p = (float*)d_ws;                        // 8192 floats
    float* q = p + B_TOT;                           // 2048 floats

    // Kernel 1: 8192 + 2048 = 10240 waves -> 2560 blocks of 256
    pq_kernel<<<(B_TOT + N_TOT) / 4, 256, 0, stream>>>(patient, disease, ak, p, q);

    // Kernel 2: 8192 / BP = 512 blocks of 256
    gat_main<<<B_TOT / BP, 256, 0, stream>>>(patient, disease, p, q, out);
}

// Round 4
// 50.247 us; speedup vs baseline: 2.9613x; 2.9613x over previous
//
#include <hip/hip_runtime.h>
#include <hip/hip_bf16.h>

#define LEAKY 0.2f
#define B_TOT 8192
#define N_TOT 2048
#define D_TOT 128
#define BM 16

typedef float f32x4 __attribute__((ext_vector_type(4)));
typedef short bf16x8 __attribute__((ext_vector_type(8)));
typedef unsigned short u16x8 __attribute__((ext_vector_type(8)));

static __device__ __forceinline__ unsigned short f2bf(float x) {
    return __builtin_bit_cast(unsigned short, __float2bfloat16(x));
}

// ---------------- fast path ----------------

// Prep: q[n] = disease[n,:] . a_n  (blocks 0..511, one wave per row)
//       DnT bf16 transpose, u32-packed [128][1024] (blocks 512..1023)
__global__ __launch_bounds__(256) void prep_kernel(const float* __restrict__ disease,
                                                   const float* __restrict__ ak,
                                                   float* __restrict__ q,
                                                   unsigned* __restrict__ DnT32) {
    const int b = blockIdx.x;
    const int tid = threadIdx.x;
    if (b < N_TOT / 4) {
        const int wave = tid >> 6, lane = tid & 63;
        const int row = b * 4 + wave;
        const float* src = disease + (size_t)row * D_TOT;
        float s = src[lane] * ak[D_TOT + lane] + src[lane + 64] * ak[D_TOT + lane + 64];
        #pragma unroll
        for (int off = 32; off; off >>= 1) s += __shfl_xor(s, off);
        if (lane == 0) q[row] = s;
    } else {
        const int g = (b - N_TOT / 4) * 256 + tid;   // 0 .. 128*1024-1
        const int col = g >> 10;
        const int nw  = g & 1023;
        float d0 = disease[(size_t)(2 * nw)     * D_TOT + col];
        float d1 = disease[(size_t)(2 * nw + 1) * D_TOT + col];
        DnT32[(size_t)col * 1024 + nw] =
            (unsigned)f2bf(d0) | ((unsigned)f2bf(d1) << 16);
    }
}

// Main: 16 rows x 128 cols per block (wave tile 16x32). Fused p/qmax/S prologue,
// barrier-free MFMA K-loop, W built in-register in A-frag layout.
__global__ __launch_bounds__(256) void gat_mfma(const float* __restrict__ patient,
                                                const float* __restrict__ ak,
                                                const float* __restrict__ q,
                                                const unsigned short* __restrict__ DnT,
                                                float* __restrict__ out) {
    __shared__ __align__(16) float q_s[N_TOT];
    __shared__ float a_s[D_TOT];
    __shared__ float p_s[BM], m_s[BM], S_s[BM];
    __shared__ float red[4];

    const int tid  = threadIdx.x;
    const int wave = tid >> 6;
    const int lane = tid & 63;
    const int b0   = blockIdx.x * BM;

    for (int i = tid; i < N_TOT; i += 256) q_s[i] = q[i];
    if (tid < D_TOT) a_s[tid] = ak[tid];
    __syncthreads();

    // p for rows [wave*4, wave*4+4)
    for (int rr = 0; rr < 4; ++rr) {
        const int row = wave * 4 + rr;
        const float* pr = patient + (size_t)(b0 + row) * D_TOT;
        float s = pr[lane] * a_s[lane] + pr[lane + 64] * a_s[lane + 64];
        #pragma unroll
        for (int off = 32; off; off >>= 1) s += __shfl_xor(s, off);
        if (lane == 0) p_s[row] = s;
    }
    // global qmax (leaky monotonic -> row max = leaky(p + qmax))
    float mx = -1e30f;
    for (int i = tid; i < N_TOT; i += 256) mx = fmaxf(mx, q_s[i]);
    #pragma unroll
    for (int off = 32; off; off >>= 1) mx = fmaxf(mx, __shfl_xor(mx, off));
    if (lane == 0) red[wave] = mx;
    __syncthreads();
    const float qmax = fmaxf(fmaxf(red[0], red[1]), fmaxf(red[2], red[3]));

    // m and S per row (wave-owned rows)
    for (int rr = 0; rr < 4; ++rr) {
        const int row = wave * 4 + rr;
        const float pv = p_s[row];
        const float xm = pv + qmax;
        const float m = fmaxf(xm, LEAKY * xm);
        float s = 0.f;
        for (int n = lane; n < N_TOT; n += 64) {
            float x = pv + q_s[n];
            float t = fmaxf(x, LEAKY * x);
            s += __expf(t - m);
        }
        #pragma unroll
        for (int off = 32; off; off >>= 1) s += __shfl_xor(s, off);
        if (lane == 0) { m_s[row] = m; S_s[row] = s; }
    }
    __syncthreads();

    // ---- barrier-free MFMA K-loop ----
    const int cl = lane & 15;      // A row / B,D col within 16-tile
    const int kg = lane >> 4;      // k-group
    const float pA = p_s[cl];
    const float mA = m_s[cl];

    const unsigned short* bp0 = DnT + (size_t)(wave * 32 + cl) * N_TOT + kg * 8;
    const unsigned short* bp1 = bp0 + (size_t)16 * N_TOT;

    f32x4 acc0{}, acc1{};

    #pragma unroll 2
    for (int k0 = 0; k0 < N_TOT; k0 += 32) {
        const float4 qa = *(const float4*)&q_s[k0 + kg * 8];
        const float4 qb = *(const float4*)&q_s[k0 + kg * 8 + 4];
        const bf16x8 bf0 = *(const bf16x8*)(bp0 + k0);
        const bf16x8 bf1 = *(const bf16x8*)(bp1 + k0);

        const float qv[8] = {qa.x, qa.y, qa.z, qa.w, qb.x, qb.y, qb.z, qb.w};
        u16x8 aw;
        #pragma unroll
        for (int j = 0; j < 8; ++j) {
            float x = pA + qv[j];
            float t = fmaxf(x, LEAKY * x);
            aw[j] = f2bf(__expf(t - mA));
        }
        const bf16x8 a0 = __builtin_bit_cast(bf16x8, aw);

        acc0 = __builtin_amdgcn_mfma_f32_16x16x32_bf16(a0, bf0, acc0, 0, 0, 0);
        acc1 = __builtin_amdgcn_mfma_f32_16x16x32_bf16(a0, bf1, acc1, 0, 0, 0);
    }

    // ---- epilogue: out = patient + acc / S ----
    #pragma unroll
    for (int i = 0; i < 4; ++i) {
        const int row = b0 + kg * 4 + i;
        const float inv = 1.0f / S_s[kg * 4 + i];
        const int colA = wave * 32 + cl;
        const int colB = colA + 16;
        out[(size_t)row * D_TOT + colA] = patient[(size_t)row * D_TOT + colA] + acc0[i] * inv;
        out[(size_t)row * D_TOT + colB] = patient[(size_t)row * D_TOT + colB] + acc1[i] * inv;
    }
}

// ---------------- fallback path (round-1, known-passing) ----------------

__global__ __launch_bounds__(256) void pq_fb(const float* __restrict__ patient,
                                             const float* __restrict__ disease,
                                             const float* __restrict__ ak,
                                             float* __restrict__ p,
                                             float* __restrict__ q) {
    int gid  = blockIdx.x * blockDim.x + threadIdx.x;
    int wid  = gid >> 6;
    int lane = gid & 63;
    const float* src;
    const float* a;
    float* dst;
    if (wid < B_TOT) {
        src = patient + (size_t)wid * D_TOT; a = ak; dst = p + wid;
    } else {
        src = disease + (size_t)(wid - B_TOT) * D_TOT; a = ak + D_TOT; dst = q + (wid - B_TOT);
    }
    float s = src[lane] * a[lane] + src[lane + 64] * a[lane + 64];
    #pragma unroll
    for (int off = 32; off; off >>= 1) s += __shfl_xor(s, off);
    if (lane == 0) *dst = s;
}

#define FBP 16
#define FNT 256
__global__ __launch_bounds__(256) void gat_fb(const float* __restrict__ patient,
                                              const float* __restrict__ disease,
                                              const float* __restrict__ p,
                                              const float* __restrict__ q,
                                              float* __restrict__ out) {
    __shared__ float q_s[N_TOT];
    __shared__ float w_s[FBP][FNT];
    __shared__ float m_s[FBP], S_s[FBP], pp_s[FBP];
    const int tid = threadIdx.x;
    const int b0  = blockIdx.x * FBP;
    for (int i = tid; i < N_TOT; i += 256) q_s[i] = q[i];
    if (tid < FBP) pp_s[tid] = p[b0 + tid];
    __syncthreads();
    const int wave = tid >> 6, lane = tid & 63;
    for (int pi = wave * 4; pi < wave * 4 + 4; ++pi) {
        float pp = pp_s[pi];
        float mx = -1e30f;
        for (int n = lane; n < N_TOT; n += 64) {
            float x = pp + q_s[n]; x = x > 0.0f ? x : LEAKY * x; mx = fmaxf(mx, x);
        }
        #pragma unroll
        for (int off = 32; off; off >>= 1) mx = fmaxf(mx, __shfl_xor(mx, off));
        float sum = 0.0f;
        for (int n = lane; n < N_TOT; n += 64) {
            float x = pp + q_s[n]; x = x > 0.0f ? x : LEAKY * x; sum += __expf(x - mx);
        }
        #pragma unroll
        for (int off = 32; off; off >>= 1) sum += __shfl_xor(sum, off);
        if (lane == 0) { m_s[pi] = mx; S_s[pi] = sum; }
    }
    __syncthreads();
    const int d2 = tid & 31;
    const int pg = tid >> 5;
    const int p0 = 2 * pg, p1 = 2 * pg + 1;
    float4 acc0 = make_float4(0.f, 0.f, 0.f, 0.f);
    float4 acc1 = make_float4(0.f, 0.f, 0.f, 0.f);
    for (int n0 = 0; n0 < N_TOT; n0 += FNT) {
        __syncthreads();
        for (int i = tid; i < FBP * FNT; i += 256) {
            int pi = i >> 8;
            int nt = i & (FNT - 1);
            float x = pp_s[pi] + q_s[n0 + nt];
            x = x > 0.0f ? x : LEAKY * x;
            w_s[pi][nt] = __expf(x - m_s[pi]);
        }
        __syncthreads();
        const float* drow = disease + (size_t)n0 * D_TOT + d2 * 4;
        #pragma unroll 4
        for (int nt = 0; nt < FNT; ++nt) {
            float4 dv = *reinterpret_cast<const float4*>(drow + (size_t)nt * D_TOT);
            float w0 = w_s[p0][nt];
            float w1 = w_s[p1][nt];
            acc0.x += w0 * dv.x; acc0.y += w0 * dv.y; acc0.z += w0 * dv.z; acc0.w += w0 * dv.w;
            acc1.x += w1 * dv.x; acc1.y += w1 * dv.y; acc1.z += w1 * dv.z; acc1.w += w1 * dv.w;
        }
    }
    const float inv0 = 1.0f / S_s[p0];
    const float inv1 = 1.0f / S_s[p1];
    {
        size_t off = (size_t)(b0 + p0) * D_TOT + d2 * 4;
        float4 pf = *reinterpret_cast<const float4*>(patient + off);
        float4 o;
        o.x = pf.x + acc0.x * inv0; o.y = pf.y + acc0.y * inv0;
        o.z = pf.z + acc0.z * inv0; o.w = pf.w + acc0.w * inv0;
        *reinterpret_cast<float4*>(reinterpret_cast<float*>(out) + off) = o;
    }
    {
        size_t off = (size_t)(b0 + p1) * D_TOT + d2 * 4;
        float4 pf = *reinterpret_cast<const float4*>(patient + off);
        float4 o;
        o.x = pf.x + acc1.x * inv1; o.y = pf.y + acc1.y * inv1;
        o.z = pf.z + acc1.z * inv1; o.w = pf.w + acc1.w * inv1;
        *reinterpret_cast<float4*>(reinterpret_cast<float*>(out) + off) = o;
    }
}

extern "C" void kernel_launch(void* const* d_in, const int* in_sizes, int n_in,
                              void* d_out, int out_size, void* d_ws, size_t ws_size,
                              hipStream_t stream) {
    const float* patient = (const float*)d_in[0];   // 8192 x 128
    const float* disease = (const float*)d_in[1];   // 2048 x 128
    const float* ak      = (const float*)d_in[2];   // 256
    float* out = (float*)d_out;

    const size_t need_fast = (size_t)512 * 1024 + 8192;   // DnT (512KB) + q (8KB)
    if (ws_size >= need_fast) {
        unsigned* DnT32 = (unsigned*)d_ws;                          // 128x1024 u32
        float*    q     = (float*)((char*)d_ws + 512 * 1024);      // 2048 f32
        prep_kernel<<<1024, 256, 0, stream>>>(disease, ak, q, DnT32);
        gat_mfma<<<B_TOT / BM, 256, 0, stream>>>(patient, ak, q,
                                                 (const unsigned short*)DnT32, out);
    } else {
        float* p = (float*)d_ws;          // 8192 f32
        float* q = p + B_TOT;             // 2048 f32
        pq_fb<<<(B_TOT + N_TOT) / 4, 256, 0, stream>>>(patient, disease, ak, p, q);
        gat_fb<<<B_TOT / FBP, 256, 0, stream>>>(patient, disease, p, q, out);
    }
}

// Round 5
// 47.341 us; speedup vs baseline: 3.1430x; 1.0614x over previous
//
#include <hip/hip_runtime.h>
#include <hip/hip_bf16.h>

#define LEAKY 0.2f
#define B_TOT 8192
#define N_TOT 2048
#define D_TOT 128
#define BM 32

typedef float f32x4 __attribute__((ext_vector_type(4)));
typedef short bf16x8 __attribute__((ext_vector_type(8)));
typedef unsigned short u16x8 __attribute__((ext_vector_type(8)));

static __device__ __forceinline__ unsigned short f2bf(float x) {
    return __builtin_bit_cast(unsigned short, __float2bfloat16(x));
}

// ---------------- fast path ----------------

// Prep: block b handles disease rows [b*32, b*32+32).
//  - LDS-tiled (padded) load, q-dots, and bf16 transpose into DnT.
__global__ __launch_bounds__(256) void prep_kernel(const float* __restrict__ disease,
                                                   const float* __restrict__ ak,
                                                   float* __restrict__ q,
                                                   unsigned* __restrict__ DnT32) {
    __shared__ float tile[32][129];   // +1 pad: column reads spread across banks
    __shared__ float a_s[D_TOT];
    const int tid = threadIdx.x;
    const int b = blockIdx.x;
    const int r0 = b * 32;

    if (tid < D_TOT) a_s[tid] = ak[D_TOT + tid];
    #pragma unroll
    for (int t = 0; t < 4; ++t) {
        int idx = tid + t * 256;          // 0..1023 float4 slots
        int row = idx >> 5;
        int cv = (idx & 31) * 4;
        float4 v = *(const float4*)(disease + (size_t)(r0 + row) * D_TOT + cv);
        tile[row][cv] = v.x; tile[row][cv + 1] = v.y;
        tile[row][cv + 2] = v.z; tile[row][cv + 3] = v.w;
    }
    __syncthreads();

    const int wave = tid >> 6, lane = tid & 63;
    #pragma unroll
    for (int rr = 0; rr < 8; ++rr) {
        int r = wave * 8 + rr;
        float s = tile[r][lane] * a_s[lane] + tile[r][lane + 64] * a_s[lane + 64];
        #pragma unroll
        for (int off = 32; off; off >>= 1) s += __shfl_xor(s, off);
        if (lane == 0) q[r0 + r] = s;
    }

    const int col = tid >> 1;
    const int i0 = (tid & 1) * 8;
    #pragma unroll
    for (int i = 0; i < 8; ++i) {
        int nwl = i0 + i;                 // local row-pair 0..15
        unsigned lo = f2bf(tile[2 * nwl][col]);
        unsigned hi = f2bf(tile[2 * nwl + 1][col]);
        DnT32[(size_t)col * (N_TOT / 2) + b * 16 + nwl] = lo | (hi << 16);
    }
}

// Main: 256 blocks x 1024 threads. BM=32 rows per block.
// 16 waves = rt(2 row-tiles) x cw(2 col-halves) x kq(4 K-quarters).
// W built in-register in A-frag layout WITHOUT exp (factorized select).
__global__ __launch_bounds__(1024, 4) void gat_mfma(const float* __restrict__ patient,
                                                    const float* __restrict__ ak,
                                                    const float* __restrict__ q,
                                                    const unsigned short* __restrict__ DnT,
                                                    float* __restrict__ out) {
    __shared__ __align__(16) float eq1_s[N_TOT];
    __shared__ __align__(16) float eq2_s[N_TOT];
    __shared__ float red_s[3][2][2][1024];   // [kq-1][rt][cw][t*256+(kg*4+i)*16+cl]
    __shared__ float a_s[D_TOT];
    __shared__ float p_s[BM], E1_s[BM], E2_s[BM], T1_s[BM], S_s[BM];
    __shared__ float red16[16];

    const int tid  = threadIdx.x;
    const int wave = tid >> 6;
    const int lane = tid & 63;
    const int b0   = blockIdx.x * BM;

    if (tid < D_TOT) a_s[tid] = ak[tid];
    __syncthreads();

    // eq1/eq2 + qmax partials (2 elements per thread)
    float mx = -1e30f;
    for (int i = tid; i < N_TOT; i += 1024) {
        float qq = q[i];
        eq1_s[i] = __expf(qq);
        eq2_s[i] = __expf(LEAKY * qq);
        mx = fmaxf(mx, qq);
    }
    #pragma unroll
    for (int off = 32; off; off >>= 1) mx = fmaxf(mx, __shfl_xor(mx, off));
    if (lane == 0) red16[wave] = mx;

    // p-dots: wave handles rows 2w, 2w+1
    #pragma unroll
    for (int rr = 0; rr < 2; ++rr) {
        const int row = wave * 2 + rr;
        const float* pr = patient + (size_t)(b0 + row) * D_TOT;
        float s = pr[lane] * a_s[lane] + pr[lane + 64] * a_s[lane + 64];
        #pragma unroll
        for (int off = 32; off; off >>= 1) s += __shfl_xor(s, off);
        if (lane == 0) p_s[row] = s;
    }
    __syncthreads();

    float qmax = red16[0];
    #pragma unroll
    for (int i = 1; i < 16; ++i) qmax = fmaxf(qmax, red16[i]);

    if (tid < BM) {
        const float pv = p_s[tid];
        const float xm = pv + qmax;
        const float m = fmaxf(xm, LEAKY * xm);    // row max (leaky monotonic)
        E1_s[tid] = __expf(pv - m);
        E2_s[tid] = __expf(LEAKY * pv - m);
        T1_s[tid] = __expf(-pv);
    }
    __syncthreads();

    // S per row: S = E1*sum(eq1 | x>0) + E2*sum(eq2 | x<=0)
    #pragma unroll
    for (int rr = 0; rr < 2; ++rr) {
        const int row = wave * 2 + rr;
        const float T1 = T1_s[row];
        float s1 = 0.f, s2 = 0.f;
        for (int n = lane; n < N_TOT; n += 64) {
            float e1 = eq1_s[n], e2 = eq2_s[n];
            bool c = e1 > T1;
            s1 += c ? e1 : 0.f;
            s2 += c ? 0.f : e2;
        }
        #pragma unroll
        for (int off = 32; off; off >>= 1) {
            s1 += __shfl_xor(s1, off);
            s2 += __shfl_xor(s2, off);
        }
        if (lane == 0) S_s[row] = E1_s[row] * s1 + E2_s[row] * s2;
    }
    __syncthreads();

    // ---- barrier-free MFMA K-loop ----
    const int cl = lane & 15;
    const int kg = lane >> 4;
    const int cw = wave & 1;          // 64-col half
    const int rt = (wave >> 1) & 1;   // 16-row tile
    const int kq = wave >> 2;         // K quarter
    const int arow = rt * 16 + cl;

    const float E1A = E1_s[arow], E2A = E2_s[arow], T1A = T1_s[arow];
    const int kbase = kq * 512;

    const unsigned short* bp[4];
    #pragma unroll
    for (int t = 0; t < 4; ++t)
        bp[t] = DnT + (size_t)(cw * 64 + t * 16 + cl) * N_TOT + kbase + kg * 8;

    f32x4 acc[4] = {};

    #pragma unroll 2
    for (int k0 = 0; k0 < 512; k0 += 32) {
        const int gk = kbase + k0 + kg * 8;
        const float4 e1a = *(const float4*)&eq1_s[gk];
        const float4 e1b = *(const float4*)&eq1_s[gk + 4];
        const float4 e2a = *(const float4*)&eq2_s[gk];
        const float4 e2b = *(const float4*)&eq2_s[gk + 4];
        bf16x8 bf[4];
        #pragma unroll
        for (int t = 0; t < 4; ++t) bf[t] = *(const bf16x8*)(bp[t] + k0);

        const float e1v[8] = {e1a.x, e1a.y, e1a.z, e1a.w, e1b.x, e1b.y, e1b.z, e1b.w};
        const float e2v[8] = {e2a.x, e2a.y, e2a.z, e2a.w, e2b.x, e2b.y, e2b.z, e2b.w};
        u16x8 aw;
        #pragma unroll
        for (int j = 0; j < 8; ++j) {
            bool c = e1v[j] > T1A;                       // == (p + q > 0)
            float w = (c ? E1A : E2A) * (c ? e1v[j] : e2v[j]);
            aw[j] = f2bf(w);
        }
        const bf16x8 a0 = __builtin_bit_cast(bf16x8, aw);

        acc[0] = __builtin_amdgcn_mfma_f32_16x16x32_bf16(a0, bf[0], acc[0], 0, 0, 0);
        acc[1] = __builtin_amdgcn_mfma_f32_16x16x32_bf16(a0, bf[1], acc[1], 0, 0, 0);
        acc[2] = __builtin_amdgcn_mfma_f32_16x16x32_bf16(a0, bf[2], acc[2], 0, 0, 0);
        acc[3] = __builtin_amdgcn_mfma_f32_16x16x32_bf16(a0, bf[3], acc[3], 0, 0, 0);
    }

    // ---- split-K reduction ----
    __syncthreads();
    if (kq > 0) {
        float* rb = &red_s[kq - 1][rt][cw][0];
        #pragma unroll
        for (int t = 0; t < 4; ++t)
            #pragma unroll
            for (int i = 0; i < 4; ++i)
                rb[t * 256 + (kg * 4 + i) * 16 + cl] = acc[t][i];
    }
    __syncthreads();
    if (kq == 0) {
        #pragma unroll
        for (int t = 0; t < 4; ++t)
            #pragma unroll
            for (int i = 0; i < 4; ++i) {
                const int idx = t * 256 + (kg * 4 + i) * 16 + cl;
                acc[t][i] += red_s[0][rt][cw][idx] + red_s[1][rt][cw][idx]
                           + red_s[2][rt][cw][idx];
            }
        float inv[4];
        #pragma unroll
        for (int i = 0; i < 4; ++i) inv[i] = 1.0f / S_s[rt * 16 + kg * 4 + i];
        #pragma unroll
        for (int t = 0; t < 4; ++t)
            #pragma unroll
            for (int i = 0; i < 4; ++i) {
                const int row = b0 + rt * 16 + kg * 4 + i;
                const int col = cw * 64 + t * 16 + cl;
                out[(size_t)row * D_TOT + col] =
                    patient[(size_t)row * D_TOT + col] + acc[t][i] * inv[i];
            }
    }
}

// ---------------- fallback path (round-1, known-passing) ----------------

__global__ __launch_bounds__(256) void pq_fb(const float* __restrict__ patient,
                                             const float* __restrict__ disease,
                                             const float* __restrict__ ak,
                                             float* __restrict__ p,
                                             float* __restrict__ q) {
    int gid  = blockIdx.x * blockDim.x + threadIdx.x;
    int wid  = gid >> 6;
    int lane = gid & 63;
    const float* src;
    const float* a;
    float* dst;
    if (wid < B_TOT) {
        src = patient + (size_t)wid * D_TOT; a = ak; dst = p + wid;
    } else {
        src = disease + (size_t)(wid - B_TOT) * D_TOT; a = ak + D_TOT; dst = q + (wid - B_TOT);
    }
    float s = src[lane] * a[lane] + src[lane + 64] * a[lane + 64];
    #pragma unroll
    for (int off = 32; off; off >>= 1) s += __shfl_xor(s, off);
    if (lane == 0) *dst = s;
}

#define FBP 16
#define FNT 256
__global__ __launch_bounds__(256) void gat_fb(const float* __restrict__ patient,
                                              const float* __restrict__ disease,
                                              const float* __restrict__ p,
                                              const float* __restrict__ q,
                                              float* __restrict__ out) {
    __shared__ float q_s[N_TOT];
    __shared__ float w_s[FBP][FNT];
    __shared__ float m_s[FBP], S_s[FBP], pp_s[FBP];
    const int tid = threadIdx.x;
    const int b0  = blockIdx.x * FBP;
    for (int i = tid; i < N_TOT; i += 256) q_s[i] = q[i];
    if (tid < FBP) pp_s[tid] = p[b0 + tid];
    __syncthreads();
    const int wave = tid >> 6, lane = tid & 63;
    for (int pi = wave * 4; pi < wave * 4 + 4; ++pi) {
        float pp = pp_s[pi];
        float mx = -1e30f;
        for (int n = lane; n < N_TOT; n += 64) {
            float x = pp + q_s[n]; x = x > 0.0f ? x : LEAKY * x; mx = fmaxf(mx, x);
        }
        #pragma unroll
        for (int off = 32; off; off >>= 1) mx = fmaxf(mx, __shfl_xor(mx, off));
        float sum = 0.0f;
        for (int n = lane; n < N_TOT; n += 64) {
            float x = pp + q_s[n]; x = x > 0.0f ? x : LEAKY * x; sum += __expf(x - mx);
        }
        #pragma unroll
        for (int off = 32; off; off >>= 1) sum += __shfl_xor(sum, off);
        if (lane == 0) { m_s[pi] = mx; S_s[pi] = sum; }
    }
    __syncthreads();
    const int d2 = tid & 31;
    const int pg = tid >> 5;
    const int p0 = 2 * pg, p1 = 2 * pg + 1;
    float4 acc0 = make_float4(0.f, 0.f, 0.f, 0.f);
    float4 acc1 = make_float4(0.f, 0.f, 0.f, 0.f);
    for (int n0 = 0; n0 < N_TOT; n0 += FNT) {
        __syncthreads();
        for (int i = tid; i < FBP * FNT; i += 256) {
            int pi = i >> 8;
            int nt = i & (FNT - 1);
            float x = pp_s[pi] + q_s[n0 + nt];
            x = x > 0.0f ? x : LEAKY * x;
            w_s[pi][nt] = __expf(x - m_s[pi]);
        }
        __syncthreads();
        const float* drow = disease + (size_t)n0 * D_TOT + d2 * 4;
        #pragma unroll 4
        for (int nt = 0; nt < FNT; ++nt) {
            float4 dv = *reinterpret_cast<const float4*>(drow + (size_t)nt * D_TOT);
            float w0 = w_s[p0][nt];
            float w1 = w_s[p1][nt];
            acc0.x += w0 * dv.x; acc0.y += w0 * dv.y; acc0.z += w0 * dv.z; acc0.w += w0 * dv.w;
            acc1.x += w1 * dv.x; acc1.y += w1 * dv.y; acc1.z += w1 * dv.z; acc1.w += w1 * dv.w;
        }
    }
    const float inv0 = 1.0f / S_s[p0];
    const float inv1 = 1.0f / S_s[p1];
    {
        size_t off = (size_t)(b0 + p0) * D_TOT + d2 * 4;
        float4 pf = *reinterpret_cast<const float4*>(patient + off);
        float4 o;
        o.x = pf.x + acc0.x * inv0; o.y = pf.y + acc0.y * inv0;
        o.z = pf.z + acc0.z * inv0; o.w = pf.w + acc0.w * inv0;
        *reinterpret_cast<float4*>(reinterpret_cast<float*>(out) + off) = o;
    }
    {
        size_t off = (size_t)(b0 + p1) * D_TOT + d2 * 4;
        float4 pf = *reinterpret_cast<const float4*>(patient + off);
        float4 o;
        o.x = pf.x + acc1.x * inv1; o.y = pf.y + acc1.y * inv1;
        o.z = pf.z + acc1.z * inv1; o.w = pf.w + acc1.w * inv1;
        *reinterpret_cast<float4*>(reinterpret_cast<float*>(out) + off) = o;
    }
}

extern "C" void kernel_launch(void* const* d_in, const int* in_sizes, int n_in,
                              void* d_out, int out_size, void* d_ws, size_t ws_size,
                              hipStream_t stream) {
    const float* patient = (const float*)d_in[0];   // 8192 x 128
    const float* disease = (const float*)d_in[1];   // 2048 x 128
    const float* ak      = (const float*)d_in[2];   // 256
    float* out = (float*)d_out;

    const size_t need_fast = (size_t)512 * 1024 + 8192;   // DnT (512KB) + q (8KB)
    if (ws_size >= need_fast) {
        unsigned* DnT32 = (unsigned*)d_ws;                          // 128x1024 u32
        float*    q     = (float*)((char*)d_ws + 512 * 1024);      // 2048 f32
        prep_kernel<<<N_TOT / 32, 256, 0, stream>>>(disease, ak, q, DnT32);
        gat_mfma<<<B_TOT / BM, 1024, 0, stream>>>(patient, ak, q,
                                                  (const unsigned short*)DnT32, out);
    } else {
        float* p = (float*)d_ws;          // 8192 f32
        float* q = p + B_TOT;             // 2048 f32
        pq_fb<<<(B_TOT + N_TOT) / 4, 256, 0, stream>>>(patient, disease, ak, p, q);
        gat_fb<<<B_TOT / FBP, 256, 0, stream>>>(patient, disease, p, q, out);
    }
}

// Round 6
// 27.715 us; speedup vs baseline: 5.3688x; 1.7081x over previous
//
#include <hip/hip_runtime.h>
#include <hip/hip_bf16.h>

#define LEAKY 0.2f
#define B_TOT 8192
#define N_TOT 2048
#define D_TOT 128
#define BM 32

typedef float f32x4 __attribute__((ext_vector_type(4)));
typedef short bf16x8 __attribute__((ext_vector_type(8)));
typedef unsigned short u16x8 __attribute__((ext_vector_type(8)));

static __device__ __forceinline__ unsigned short f2bf(float x) {
    return __builtin_bit_cast(unsigned short, __float2bfloat16(x));
}

// ---------------- fast path ----------------

// Prep: block b handles disease rows (= k values) [b*32, b*32+32).
// Writes DnTf in MFMA-B-fragment order: uint4 index (kt*8+ct)*64 + kg*16 + cl
// holds bf16 pairs for B[k=kt*32+kg*8+j][col=ct*16+cl], j=0..7.
// Consumer wave reads one fragment as 64 lanes x 16B contiguous (coalesced).
__global__ __launch_bounds__(256) void prep_kernel(const float* __restrict__ disease,
                                                   const float* __restrict__ ak,
                                                   float* __restrict__ q,
                                                   uint4* __restrict__ DnTf) {
    __shared__ float tile[32][129];   // +1 pad
    __shared__ float a_s[D_TOT];
    const int tid = threadIdx.x;
    const int b = blockIdx.x;
    const int r0 = b * 32;

    if (tid < D_TOT) a_s[tid] = ak[D_TOT + tid];
    #pragma unroll
    for (int t = 0; t < 4; ++t) {
        int idx = tid + t * 256;          // 0..1023 float4 slots
        int row = idx >> 5;
        int cv = (idx & 31) * 4;
        float4 v = *(const float4*)(disease + (size_t)(r0 + row) * D_TOT + cv);
        tile[row][cv] = v.x; tile[row][cv + 1] = v.y;
        tile[row][cv + 2] = v.z; tile[row][cv + 3] = v.w;
    }
    __syncthreads();

    const int wave = tid >> 6, lane = tid & 63;
    #pragma unroll
    for (int rr = 0; rr < 8; ++rr) {
        int r = wave * 8 + rr;
        float s = tile[r][lane] * a_s[lane] + tile[r][lane + 64] * a_s[lane + 64];
        #pragma unroll
        for (int off = 32; off; off >>= 1) s += __shfl_xor(s, off);
        if (lane == 0) q[r0 + r] = s;
    }

    // fragment writes: 512 16B chunks, 2 per thread, wave-contiguous
    #pragma unroll
    for (int h = 0; h < 2; ++h) {
        const int c  = tid + h * 256;     // 0..511
        const int kg = c >> 7;            // 0..3
        const int col = c & 127;
        const int ct = col >> 4, cl = col & 15;
        unsigned u[4];
        #pragma unroll
        for (int jj = 0; jj < 4; ++jj) {
            unsigned lo = f2bf(tile[kg * 8 + 2 * jj][col]);
            unsigned hi = f2bf(tile[kg * 8 + 2 * jj + 1][col]);
            u[jj] = lo | (hi << 16);
        }
        DnTf[((size_t)b * 8 + ct) * 64 + kg * 16 + cl] = make_uint4(u[0], u[1], u[2], u[3]);
    }
}

// Main: 256 blocks x 1024 threads. BM=32 rows per block.
// 16 waves = rt(2 row-tiles) x cw(2 col-halves) x kq(4 K-quarters).
// W built in-register in A-frag layout WITHOUT exp (factorized select).
// B fragments read coalesced from fragment-ordered DnTf.
__global__ __launch_bounds__(1024, 4) void gat_mfma(const float* __restrict__ patient,
                                                    const float* __restrict__ ak,
                                                    const float* __restrict__ q,
                                                    const unsigned short* __restrict__ DnTb,
                                                    float* __restrict__ out) {
    __shared__ __align__(16) float eq1_s[N_TOT];
    __shared__ __align__(16) float eq2_s[N_TOT];
    __shared__ float red_s[3][2][2][1024];   // [kq-1][rt][cw][t*256+(kg*4+i)*16+cl]
    __shared__ float a_s[D_TOT];
    __shared__ float p_s[BM], E1_s[BM], E2_s[BM], T1_s[BM], S_s[BM];
    __shared__ float red16[16];

    const int tid  = threadIdx.x;
    const int wave = tid >> 6;
    const int lane = tid & 63;
    const int b0   = blockIdx.x * BM;

    if (tid < D_TOT) a_s[tid] = ak[tid];
    __syncthreads();

    // eq1/eq2 + qmax partials
    float mx = -1e30f;
    for (int i = tid; i < N_TOT; i += 1024) {
        float qq = q[i];
        eq1_s[i] = __expf(qq);
        eq2_s[i] = __expf(LEAKY * qq);
        mx = fmaxf(mx, qq);
    }
    #pragma unroll
    for (int off = 32; off; off >>= 1) mx = fmaxf(mx, __shfl_xor(mx, off));
    if (lane == 0) red16[wave] = mx;

    // p-dots: wave handles rows 2w, 2w+1
    #pragma unroll
    for (int rr = 0; rr < 2; ++rr) {
        const int row = wave * 2 + rr;
        const float* pr = patient + (size_t)(b0 + row) * D_TOT;
        float s = pr[lane] * a_s[lane] + pr[lane + 64] * a_s[lane + 64];
        #pragma unroll
        for (int off = 32; off; off >>= 1) s += __shfl_xor(s, off);
        if (lane == 0) p_s[row] = s;
    }
    __syncthreads();

    float qmax = red16[0];
    #pragma unroll
    for (int i = 1; i < 16; ++i) qmax = fmaxf(qmax, red16[i]);

    if (tid < BM) {
        const float pv = p_s[tid];
        const float xm = pv + qmax;
        const float m = fmaxf(xm, LEAKY * xm);    // row max (leaky monotonic)
        E1_s[tid] = __expf(pv - m);
        E2_s[tid] = __expf(LEAKY * pv - m);
        T1_s[tid] = __expf(-pv);
    }
    __syncthreads();

    // S per row: S = E1*sum(eq1 | x>0) + E2*sum(eq2 | x<=0)
    #pragma unroll
    for (int rr = 0; rr < 2; ++rr) {
        const int row = wave * 2 + rr;
        const float T1 = T1_s[row];
        float s1 = 0.f, s2 = 0.f;
        for (int n = lane; n < N_TOT; n += 64) {
            float e1 = eq1_s[n], e2 = eq2_s[n];
            bool c = e1 > T1;
            s1 += c ? e1 : 0.f;
            s2 += c ? 0.f : e2;
        }
        #pragma unroll
        for (int off = 32; off; off >>= 1) {
            s1 += __shfl_xor(s1, off);
            s2 += __shfl_xor(s2, off);
        }
        if (lane == 0) S_s[row] = E1_s[row] * s1 + E2_s[row] * s2;
    }
    __syncthreads();

    // ---- barrier-free MFMA K-loop ----
    const int cl = lane & 15;
    const int kg = lane >> 4;
    const int cw = wave & 1;          // 64-col half
    const int rt = (wave >> 1) & 1;   // 16-row tile
    const int kq = wave >> 2;         // K quarter
    const int arow = rt * 16 + cl;

    const float E1A = E1_s[arow], E2A = E2_s[arow], T1A = T1_s[arow];

    f32x4 acc[4] = {};

    #pragma unroll 4
    for (int kt = kq * 16; kt < kq * 16 + 16; ++kt) {
        const int gk = kt * 32 + kg * 8;
        const float4 e1a = *(const float4*)&eq1_s[gk];
        const float4 e1b = *(const float4*)&eq1_s[gk + 4];
        const float4 e2a = *(const float4*)&eq2_s[gk];
        const float4 e2b = *(const float4*)&eq2_s[gk + 4];
        bf16x8 bf[4];
        #pragma unroll
        for (int t = 0; t < 4; ++t)
            bf[t] = *(const bf16x8*)(DnTb + (((size_t)kt * 8 + cw * 4 + t) * 64 + lane) * 8);

        const float e1v[8] = {e1a.x, e1a.y, e1a.z, e1a.w, e1b.x, e1b.y, e1b.z, e1b.w};
        const float e2v[8] = {e2a.x, e2a.y, e2a.z, e2a.w, e2b.x, e2b.y, e2b.z, e2b.w};
        u16x8 aw;
        #pragma unroll
        for (int j = 0; j < 8; ++j) {
            bool c = e1v[j] > T1A;                       // == (p + q > 0)
            float w = (c ? E1A : E2A) * (c ? e1v[j] : e2v[j]);
            aw[j] = f2bf(w);
        }
        const bf16x8 a0 = __builtin_bit_cast(bf16x8, aw);

        acc[0] = __builtin_amdgcn_mfma_f32_16x16x32_bf16(a0, bf[0], acc[0], 0, 0, 0);
        acc[1] = __builtin_amdgcn_mfma_f32_16x16x32_bf16(a0, bf[1], acc[1], 0, 0, 0);
        acc[2] = __builtin_amdgcn_mfma_f32_16x16x32_bf16(a0, bf[2], acc[2], 0, 0, 0);
        acc[3] = __builtin_amdgcn_mfma_f32_16x16x32_bf16(a0, bf[3], acc[3], 0, 0, 0);
    }

    // ---- split-K reduction ----
    __syncthreads();
    if (kq > 0) {
        float* rb = &red_s[kq - 1][rt][cw][0];
        #pragma unroll
        for (int t = 0; t < 4; ++t)
            #pragma unroll
            for (int i = 0; i < 4; ++i)
                rb[t * 256 + (kg * 4 + i) * 16 + cl] = acc[t][i];
    }
    __syncthreads();
    if (kq == 0) {
        #pragma unroll
        for (int t = 0; t < 4; ++t)
            #pragma unroll
            for (int i = 0; i < 4; ++i) {
                const int idx = t * 256 + (kg * 4 + i) * 16 + cl;
                acc[t][i] += red_s[0][rt][cw][idx] + red_s[1][rt][cw][idx]
                           + red_s[2][rt][cw][idx];
            }
        float inv[4];
        #pragma unroll
        for (int i = 0; i < 4; ++i) inv[i] = 1.0f / S_s[rt * 16 + kg * 4 + i];
        #pragma unroll
        for (int t = 0; t < 4; ++t)
            #pragma unroll
            for (int i = 0; i < 4; ++i) {
                const int row = b0 + rt * 16 + kg * 4 + i;
                const int col = cw * 64 + t * 16 + cl;
                out[(size_t)row * D_TOT + col] =
                    patient[(size_t)row * D_TOT + col] + acc[t][i] * inv[i];
            }
    }
}

// ---------------- fallback path (round-1, known-passing) ----------------

__global__ __launch_bounds__(256) void pq_fb(const float* __restrict__ patient,
                                             const float* __restrict__ disease,
                                             const float* __restrict__ ak,
                                             float* __restrict__ p,
                                             float* __restrict__ q) {
    int gid  = blockIdx.x * blockDim.x + threadIdx.x;
    int wid  = gid >> 6;
    int lane = gid & 63;
    const float* src;
    const float* a;
    float* dst;
    if (wid < B_TOT) {
        src = patient + (size_t)wid * D_TOT; a = ak; dst = p + wid;
    } else {
        src = disease + (size_t)(wid - B_TOT) * D_TOT; a = ak + D_TOT; dst = q + (wid - B_TOT);
    }
    float s = src[lane] * a[lane] + src[lane + 64] * a[lane + 64];
    #pragma unroll
    for (int off = 32; off; off >>= 1) s += __shfl_xor(s, off);
    if (lane == 0) *dst = s;
}

#define FBP 16
#define FNT 256
__global__ __launch_bounds__(256) void gat_fb(const float* __restrict__ patient,
                                              const float* __restrict__ disease,
                                              const float* __restrict__ p,
                                              const float* __restrict__ q,
                                              float* __restrict__ out) {
    __shared__ float q_s[N_TOT];
    __shared__ float w_s[FBP][FNT];
    __shared__ float m_s[FBP], S_s[FBP], pp_s[FBP];
    const int tid = threadIdx.x;
    const int b0  = blockIdx.x * FBP;
    for (int i = tid; i < N_TOT; i += 256) q_s[i] = q[i];
    if (tid < FBP) pp_s[tid] = p[b0 + tid];
    __syncthreads();
    const int wave = tid >> 6, lane = tid & 63;
    for (int pi = wave * 4; pi < wave * 4 + 4; ++pi) {
        float pp = pp_s[pi];
        float mx = -1e30f;
        for (int n = lane; n < N_TOT; n += 64) {
            float x = pp + q_s[n]; x = x > 0.0f ? x : LEAKY * x; mx = fmaxf(mx, x);
        }
        #pragma unroll
        for (int off = 32; off; off >>= 1) mx = fmaxf(mx, __shfl_xor(mx, off));
        float sum = 0.0f;
        for (int n = lane; n < N_TOT; n += 64) {
            float x = pp + q_s[n]; x = x > 0.0f ? x : LEAKY * x; sum += __expf(x - mx);
        }
        #pragma unroll
        for (int off = 32; off; off >>= 1) sum += __shfl_xor(sum, off);
        if (lane == 0) { m_s[pi] = mx; S_s[pi] = sum; }
    }
    __syncthreads();
    const int d2 = tid & 31;
    const int pg = tid >> 5;
    const int p0 = 2 * pg, p1 = 2 * pg + 1;
    float4 acc0 = make_float4(0.f, 0.f, 0.f, 0.f);
    float4 acc1 = make_float4(0.f, 0.f, 0.f, 0.f);
    for (int n0 = 0; n0 < N_TOT; n0 += FNT) {
        __syncthreads();
        for (int i = tid; i < FBP * FNT; i += 256) {
            int pi = i >> 8;
            int nt = i & (FNT - 1);
            float x = pp_s[pi] + q_s[n0 + nt];
            x = x > 0.0f ? x : LEAKY * x;
            w_s[pi][nt] = __expf(x - m_s[pi]);
        }
        __syncthreads();
        const float* drow = disease + (size_t)n0 * D_TOT + d2 * 4;
        #pragma unroll 4
        for (int nt = 0; nt < FNT; ++nt) {
            float4 dv = *reinterpret_cast<const float4*>(drow + (size_t)nt * D_TOT);
            float w0 = w_s[p0][nt];
            float w1 = w_s[p1][nt];
            acc0.x += w0 * dv.x; acc0.y += w0 * dv.y; acc0.z += w0 * dv.z; acc0.w += w0 * dv.w;
            acc1.x += w1 * dv.x; acc1.y += w1 * dv.y; acc1.z += w1 * dv.z; acc1.w += w1 * dv.w;
        }
    }
    const float inv0 = 1.0f / S_s[p0];
    const float inv1 = 1.0f / S_s[p1];
    {
        size_t off = (size_t)(b0 + p0) * D_TOT + d2 * 4;
        float4 pf = *reinterpret_cast<const float4*>(patient + off);
        float4 o;
        o.x = pf.x + acc0.x * inv0; o.y = pf.y + acc0.y * inv0;
        o.z = pf.z + acc0.z * inv0; o.w = pf.w + acc0.w * inv0;
        *reinterpret_cast<float4*>(reinterpret_cast<float*>(out) + off) = o;
    }
    {
        size_t off = (size_t)(b0 + p1) * D_TOT + d2 * 4;
        float4 pf = *reinterpret_cast<const float4*>(patient + off);
        float4 o;
        o.x = pf.x + acc1.x * inv1; o.y = pf.y + acc1.y * inv1;
        o.z = pf.z + acc1.z * inv1; o.w = pf.w + acc1.w * inv1;
        *reinterpret_cast<float4*>(reinterpret_cast<float*>(out) + off) = o;
    }
}

extern "C" void kernel_launch(void* const* d_in, const int* in_sizes, int n_in,
                              void* d_out, int out_size, void* d_ws, size_t ws_size,
                              hipStream_t stream) {
    const float* patient = (const float*)d_in[0];   // 8192 x 128
    const float* disease = (const float*)d_in[1];   // 2048 x 128
    const float* ak      = (const float*)d_in[2];   // 256
    float* out = (float*)d_out;

    const size_t need_fast = (size_t)512 * 1024 + 8192;   // DnTf (512KB) + q (8KB)
    if (ws_size >= need_fast) {
        uint4* DnTf = (uint4*)d_ws;                          // 64x8x64 uint4 = 512KB
        float* q    = (float*)((char*)d_ws + 512 * 1024);    // 2048 f32
        prep_kernel<<<N_TOT / 32, 256, 0, stream>>>(disease, ak, q, DnTf);
        gat_mfma<<<B_TOT / BM, 1024, 0, stream>>>(patient, ak, q,
                                                  (const unsigned short*)DnTf, out);
    } else {
        float* p = (float*)d_ws;          // 8192 f32
        float* q = p + B_TOT;             // 2048 f32
        pq_fb<<<(B_TOT + N_TOT) / 4, 256, 0, stream>>>(patient, disease, ak, p, q);
        gat_fb<<<B_TOT / FBP, 256, 0, stream>>>(patient, disease, p, q, out);
    }
}